// Round 6
// baseline (280.263 us; speedup 1.0000x reference)
//
#include <hip/hip_runtime.h>
#include <math.h>

// Problem constants
#define B_ 2
#define L_ 2048
#define S_ 2048
#define E_ 1024
#define H_ 16
#define D_ 64
#define SC_ 0.180336880111120f  // (1/sqrt(64)) * log2(e), folded into Q projection

typedef unsigned short u16;
typedef unsigned int u32;
typedef __attribute__((ext_vector_type(8))) short short8;    // 8 bf16 (4 VGPRs)
typedef __attribute__((ext_vector_type(4))) float floatx4;   // 16x16 accum

__device__ __forceinline__ u16 f2bf(float f) {
    union { float f; unsigned u; } a; a.f = f;
    unsigned r = a.u + 0x7FFFu + ((a.u >> 16) & 1u);  // RNE
    return (u16)(r >> 16);
}

// pack two f32 -> bf16x2 (RNE), single instruction
__device__ __forceinline__ u32 cvt_pk_bf16(float lo, float hi) {
    u32 d;
    asm("v_cvt_pk_bf16_f32 %0, %1, %2" : "=v"(d) : "v"(lo), "v"(hi));
    return d;
}

// async global->LDS, 16B per lane; LDS dest = wave-uniform base + lane*16
__device__ __forceinline__ void glds16(const u16* g, u16* l) {
    __builtin_amdgcn_global_load_lds(
        (const __attribute__((address_space(1))) void*)g,
        (__attribute__((address_space(3))) void*)l, 16, 0, 0);
}

// ---------------------------------------------------------------------------
// Weight transpose+cast: Wt[n][k] = bf16(W[k][n]); grid.z selects weight
// ---------------------------------------------------------------------------
__global__ void transpose_cast_kernel(const float* __restrict__ Wq, const float* __restrict__ Wk,
                                      const float* __restrict__ Wv, const float* __restrict__ Wp,
                                      u16* __restrict__ WqT, u16* __restrict__ WkT,
                                      u16* __restrict__ WvT, u16* __restrict__ WpT) {
    const int z = blockIdx.z;
    const float* W = z == 0 ? Wq : (z == 1 ? Wk : (z == 2 ? Wv : Wp));
    u16* Wt = z == 0 ? WqT : (z == 1 ? WkT : (z == 2 ? WvT : WpT));
    __shared__ float tile[32][33];
    const int bx = blockIdx.x * 32, by = blockIdx.y * 32;
    const int tx = threadIdx.x, ty = threadIdx.y;  // block (32, 8)
#pragma unroll
    for (int j = 0; j < 4; ++j)
        tile[ty + j * 8][tx] = W[(size_t)(by + ty + j * 8) * E_ + bx + tx];
    __syncthreads();
#pragma unroll
    for (int j = 0; j < 4; ++j)
        Wt[(size_t)(bx + ty + j * 8) * E_ + by + tx] = f2bf(tile[tx][ty + j * 8]);
}

// ---------------------------------------------------------------------------
// Fused QKV projection GEMM: BM=128 BN=128 BK=64, 256 threads, wave-tile
// 64x64 (4x4 16x16x32 accum), DOUBLE-buffered LDS, 1 barrier/iter.
// A is f32 (x or ctx), converted to bf16 during staging (VGPR prefetch ->
// post-MFMA convert + swizzled ds_write). B via swizzled glds16.
// XOR swizzle: LDS unit u of row r holds global unit u ^ (r&7).
// grid (8, 32, 3): z=0: Q=(x Wq+bq)*SC -> Qb ; z=1: K -> Kb ; z=2: V -> Vtb
// (V transposed: Vt[b][col][s]).
// ---------------------------------------------------------------------------
__global__ __launch_bounds__(256, 2) void qkv_gemm_kernel(
    const float* __restrict__ x, const float* __restrict__ ctx,
    const u16* __restrict__ WqT, const u16* __restrict__ WkT, const u16* __restrict__ WvT,
    const float* __restrict__ bq, const float* __restrict__ bk, const float* __restrict__ bv,
    u16* __restrict__ Qb, u16* __restrict__ Kb, u16* __restrict__ Vtb) {
    __shared__ __align__(16) u16 As[2][128 * 64];  // 2 x 16 KB
    __shared__ __align__(16) u16 Bs[2][128 * 64];  // 2 x 16 KB

    const int z = blockIdx.z;
    const float* A  = z == 0 ? x : ctx;
    const u16* Bt = z == 0 ? WqT : (z == 1 ? WkT : WvT);
    const float* bias = z == 0 ? bq : (z == 1 ? bk : bv);
    const float scale = z == 0 ? SC_ : 1.0f;

    const int tid = threadIdx.x;
    const int lane = tid & 63;
    const int wv = tid >> 6;
    const int wm = wv >> 1, wn = wv & 1;
    const int qd = lane >> 4, lr = lane & 15;
    const int m0 = blockIdx.y * 128, n0 = blockIdx.x * 128;
    const int lrow = lane >> 3;        // 0..7
    const int gu = (lane & 7) ^ lrow;  // swizzled global 16B-unit (B staging)
    const int arow = tid >> 3;         // 0..31 (A staging row base)
    const int au = tid & 7;            // A staging 8-f32 unit

    floatx4 acc[4][4];
#pragma unroll
    for (int i = 0; i < 4; ++i)
#pragma unroll
        for (int j = 0; j < 4; ++j) {
            floatx4 zz = {0.f, 0.f, 0.f, 0.f};
            acc[i][j] = zz;
        }

    float4 av[4][2];  // A prefetch registers (32 f32)

#define LOAD_A(kb)                                                                 \
    {                                                                              \
        _Pragma("unroll") for (int c2 = 0; c2 < 4; ++c2) {                         \
            const float* src = A + (size_t)(m0 + arow + c2 * 32) * E_ + (kb) + au * 8; \
            av[c2][0] = *(const float4*)src;                                       \
            av[c2][1] = *(const float4*)(src + 4);                                 \
        }                                                                          \
    }

#define WRITE_A(buf)                                                               \
    {                                                                              \
        _Pragma("unroll") for (int c2 = 0; c2 < 4; ++c2) {                         \
            int row = arow + c2 * 32;                                              \
            uint4 o;                                                               \
            o.x = cvt_pk_bf16(av[c2][0].x, av[c2][0].y);                           \
            o.y = cvt_pk_bf16(av[c2][0].z, av[c2][0].w);                           \
            o.z = cvt_pk_bf16(av[c2][1].x, av[c2][1].y);                           \
            o.w = cvt_pk_bf16(av[c2][1].z, av[c2][1].w);                           \
            *(uint4*)(&As[buf][row * 64 + (au ^ (row & 7)) * 8]) = o;              \
        }                                                                          \
    }

#define STAGE_B(buf, kb)                                                           \
    {                                                                              \
        _Pragma("unroll") for (int j = 0; j < 4; ++j) {                            \
            int c = wv * 4 + j;                                                    \
            glds16(Bt + (size_t)(n0 + c * 8 + lrow) * E_ + (kb) + gu * 8,          \
                   &Bs[buf][c * 512]);                                             \
        }                                                                          \
    }

    LOAD_A(0)
    STAGE_B(0, 0)
    WRITE_A(0)
    __syncthreads();  // tile 0 ready (ds_writes lgkm + glds vmcnt drained)

    for (int t = 0; t < 16; ++t) {
        const int cur = t & 1;
        if (t + 1 < 16) {
            STAGE_B(cur ^ 1, (t + 1) * 64)
            LOAD_A((t + 1) * 64)
        }

        short8 af[4][2], bf[4][2];
#pragma unroll
        for (int mi = 0; mi < 4; ++mi)
#pragma unroll
            for (int kk = 0; kk < 2; ++kk) {
                int row = wm * 64 + mi * 16 + lr;
                int u = (kk * 4 + qd) ^ (lr & 7);
                af[mi][kk] = *(const short8*)(&As[cur][row * 64 + u * 8]);
            }
#pragma unroll
        for (int ni = 0; ni < 4; ++ni)
#pragma unroll
            for (int kk = 0; kk < 2; ++kk) {
                int row = wn * 64 + ni * 16 + lr;
                int u = (kk * 4 + qd) ^ (lr & 7);
                bf[ni][kk] = *(const short8*)(&Bs[cur][row * 64 + u * 8]);
            }
#pragma unroll
        for (int kk = 0; kk < 2; ++kk)
#pragma unroll
            for (int mi = 0; mi < 4; ++mi)
#pragma unroll
                for (int ni = 0; ni < 4; ++ni)
                    acc[mi][ni] = __builtin_amdgcn_mfma_f32_16x16x32_bf16(
                        af[mi][kk], bf[ni][kk], acc[mi][ni], 0, 0, 0);

        if (t + 1 < 16) WRITE_A(cur ^ 1)
        __syncthreads();  // readers done with cur; next tile (glds+ds_write) drained
    }

    // epilogue: C/D row = qd*4+r, col = lane&15
    u16* Cq = z == 0 ? Qb : Kb;
#pragma unroll
    for (int mi = 0; mi < 4; ++mi) {
#pragma unroll
        for (int ni = 0; ni < 4; ++ni) {
            int col = n0 + wn * 64 + ni * 16 + lr;
            float bv_ = bias[col];
            if (z == 2) {
                int row0 = m0 + wm * 64 + mi * 16 + qd * 4;
                int bidx = row0 >> 11;
                int sloc = row0 & (S_ - 1);
                u16 h0 = f2bf(acc[mi][ni][0] + bv_);
                u16 h1 = f2bf(acc[mi][ni][1] + bv_);
                u16 h2 = f2bf(acc[mi][ni][2] + bv_);
                u16 h3 = f2bf(acc[mi][ni][3] + bv_);
                uint2 pk;
                pk.x = h0 | ((unsigned)h1 << 16);
                pk.y = h2 | ((unsigned)h3 << 16);
                *(uint2*)&Vtb[((size_t)(bidx * E_ + col)) * S_ + sloc] = pk;
            } else {
#pragma unroll
                for (int r = 0; r < 4; ++r) {
                    int row = m0 + wm * 64 + mi * 16 + qd * 4 + r;
                    Cq[(size_t)row * E_ + col] = f2bf((acc[mi][ni][r] + bv_) * scale);
                }
            }
        }
    }
#undef LOAD_A
#undef WRITE_A
#undef STAGE_B
}

// ---------------------------------------------------------------------------
// Flash attention (r5-verified math + double-buffered K/V, 1 barrier/iter):
// grid (L/128, B*H, 2), 256 threads (4 waves). Wave w owns Q rows
// [w*32, w*32+32). Fixed-reference softmax (M=0; scale folded into Q):
// p = exp2(qk'). P round-trips through wave-private LDS rows (PSTR=68).
// K row-major and V^T staged via XOR-swizzled glds (conflict-free b128).
// Outputs: NORMALIZED O-partial (bf16) + l-partial (f32).
// ---------------------------------------------------------------------------
#define PSTR 68  // P/Q LDS row stride in halfwords

__global__ __launch_bounds__(256, 3) void flash_attn_kernel(
    const u16* __restrict__ Q, const u16* __restrict__ Kg,
    const u16* __restrict__ Vtg, u16* __restrict__ Opart, float* __restrict__ lpart) {
    __shared__ __align__(16) u16 Ps[128 * PSTR];  // Q tile then P (17408 B)
    __shared__ __align__(16) u16 Ks[2][64 * 64];  // 2 x 8 KB (swizzled)
    __shared__ __align__(16) u16 Vs[2][64 * 64];  // 2 x 8 KB, V^T layout [d][s]

    const int tid = threadIdx.x;
    const int lane = tid & 63;
    const int wv = tid >> 6;
    const int qd = lane >> 4, lr = lane & 15;
    const int b = blockIdx.y >> 4, h = blockIdx.y & 15;
    const int q0 = blockIdx.x * 128;
    const int z = blockIdx.z;
    const int sbeg = z * (S_ / 2);

    u16* Op = Opart + (size_t)z * (B_ * L_ * E_);
    float* lp = lpart + (size_t)z * (B_ * H_ * L_);

    const u16* Qbase = Q + (size_t)(b * L_ + q0) * E_ + h * D_;
    const u16* Kbase = Kg + (size_t)(b * S_) * E_ + h * D_;
    const u16* Vbase = Vtg + (size_t)(b * E_ + h * D_) * S_;  // rows=d, cols=s

    const int srow = tid >> 3;        // 0..31
    const int scol = (tid & 7) * 8;   // 0..56
    const int lrow = lane >> 3;       // 0..7
    const int gu = (lane & 7) ^ lrow; // swizzled global 16B-unit

    // issue K/V tile 0 loads first (in flight during Q staging)
#pragma unroll
    for (int j = 0; j < 2; ++j) {
        int c = wv * 2 + j;
        glds16(Kbase + (size_t)(sbeg + c * 8 + lrow) * E_ + gu * 8, &Ks[0][c * 512]);
        glds16(Vbase + (size_t)(c * 8 + lrow) * S_ + sbeg + gu * 8, &Vs[0][c * 512]);
    }

    // stage Q tile (128 x 64) at stride PSTR
#pragma unroll
    for (int c = 0; c < 4; ++c) {
        int row = srow + c * 32;
        *(uint4*)(&Ps[row * PSTR + scol]) = *(const uint4*)(Qbase + (size_t)row * E_ + scol);
    }
    __syncthreads();  // Q staged; K/V tile 0 landed

    short8 qf[2][2];
#pragma unroll
    for (int mi = 0; mi < 2; ++mi)
#pragma unroll
        for (int kk = 0; kk < 2; ++kk)
            qf[mi][kk] = *(const short8*)(&Ps[(wv * 32 + mi * 16 + lr) * PSTR + kk * 32 + qd * 8]);

    floatx4 o_acc[2][4];
    float l_acc[2][4];
#pragma unroll
    for (int mi = 0; mi < 2; ++mi)
#pragma unroll
        for (int nt = 0; nt < 4; ++nt) {
            floatx4 z4 = {0.f, 0.f, 0.f, 0.f};
            o_acc[mi][nt] = z4;
        }
#pragma unroll
    for (int mi = 0; mi < 2; ++mi)
#pragma unroll
        for (int r = 0; r < 4; ++r) l_acc[mi][r] = 0.f;

    const int NIT = (S_ / 2) / 64;  // 16

    for (int it = 0; it < NIT; ++it) {
        const int cur = it & 1;
        // prefetch next K/V tile into the other buffer (in flight during compute)
        if (it + 1 < NIT) {
            int s1 = sbeg + (it + 1) * 64;
#pragma unroll
            for (int j = 0; j < 2; ++j) {
                int c = wv * 2 + j;
                glds16(Kbase + (size_t)(s1 + c * 8 + lrow) * E_ + gu * 8, &Ks[cur ^ 1][c * 512]);
                glds16(Vbase + (size_t)(c * 8 + lrow) * S_ + s1 + gu * 8, &Vs[cur ^ 1][c * 512]);
            }
        }

        // ---- S' = Q K^T (scale already folded into Q) ----
        floatx4 s_[2][4];
#pragma unroll
        for (int nt = 0; nt < 4; ++nt) {
            int krow = nt * 16 + lr;
            short8 kb0 = *(const short8*)(&Ks[cur][krow * 64 + ((qd) ^ (lr & 7)) * 8]);
            short8 kb1 = *(const short8*)(&Ks[cur][krow * 64 + ((4 + qd) ^ (lr & 7)) * 8]);
#pragma unroll
            for (int mi = 0; mi < 2; ++mi) {
                floatx4 zz = {0.f, 0.f, 0.f, 0.f};
                zz = __builtin_amdgcn_mfma_f32_16x16x32_bf16(qf[mi][0], kb0, zz, 0, 0, 0);
                zz = __builtin_amdgcn_mfma_f32_16x16x32_bf16(qf[mi][1], kb1, zz, 0, 0, 0);
                s_[mi][nt] = zz;
            }
        }

        // ---- p = exp2(s'); accumulate l; write P (wave-private rows) ----
#pragma unroll
        for (int mi = 0; mi < 2; ++mi)
#pragma unroll
            for (int nt = 0; nt < 4; ++nt)
#pragma unroll
                for (int r = 0; r < 4; ++r) {
                    float p = __builtin_amdgcn_exp2f(s_[mi][nt][r]);
                    l_acc[mi][r] += p;
                    Ps[(wv * 32 + mi * 16 + qd * 4 + r) * PSTR + nt * 16 + lr] = f2bf(p);
                }
        asm volatile("s_waitcnt lgkmcnt(0)" ::: "memory");  // order P write->read (wave-local)

        // ---- O += P V ----
        short8 pf[2][2];
#pragma unroll
        for (int mi = 0; mi < 2; ++mi)
#pragma unroll
            for (int kk = 0; kk < 2; ++kk)
                pf[mi][kk] = *(const short8*)(&Ps[(wv * 32 + mi * 16 + lr) * PSTR + kk * 32 + qd * 8]);
#pragma unroll
        for (int nt = 0; nt < 4; ++nt) {
            int vrow = nt * 16 + lr;
            short8 vb0 = *(const short8*)(&Vs[cur][vrow * 64 + ((qd) ^ (lr & 7)) * 8]);
            short8 vb1 = *(const short8*)(&Vs[cur][vrow * 64 + ((4 + qd) ^ (lr & 7)) * 8]);
#pragma unroll
            for (int mi = 0; mi < 2; ++mi) {
                o_acc[mi][nt] = __builtin_amdgcn_mfma_f32_16x16x32_bf16(pf[mi][0], vb0, o_acc[mi][nt], 0, 0, 0);
                o_acc[mi][nt] = __builtin_amdgcn_mfma_f32_16x16x32_bf16(pf[mi][1], vb1, o_acc[mi][nt], 0, 0, 0);
            }
        }

        __syncthreads();  // readers done with cur; prefetch into cur^1 drained
    }

    // ---- epilogue: l reduction; write l and NORMALIZED O partial ----
    float linv[2][4];
#pragma unroll
    for (int mi = 0; mi < 2; ++mi)
#pragma unroll
        for (int r = 0; r < 4; ++r) {
            float l = l_acc[mi][r];
#pragma unroll
            for (int st = 1; st < 16; st <<= 1) l += __shfl_xor(l, st);
            if (lr == 0)
                lp[(size_t)(b * H_ + h) * L_ + q0 + wv * 32 + mi * 16 + qd * 4 + r] = l;
            linv[mi][r] = 1.0f / l;
        }

#pragma unroll
    for (int mi = 0; mi < 2; ++mi)
#pragma unroll
        for (int nt = 0; nt < 4; ++nt)
#pragma unroll
            for (int r = 0; r < 4; ++r) {
                int row = q0 + wv * 32 + mi * 16 + qd * 4 + r;
                int col = h * D_ + nt * 16 + lr;
                Op[(size_t)(b * L_ + row) * E_ + col] = f2bf(o_acc[mi][nt][r] * linv[mi][r]);
            }
}

// ---------------------------------------------------------------------------
// Output GEMM with fused split-S combine: A = w1*O1~ + w2*O2~ (normalized
// partials, wi = li/(l1+l2), per (row, head=k-iter)). C = A*WpT^T + bp, f32.
// BM=128 BN=128 BK=64, DOUBLE-buffered LDS, 1 barrier/iter. A combine is
// VGPR-prefetched at iter top, applied post-MFMA. B via swizzled glds16.
// ---------------------------------------------------------------------------
__global__ __launch_bounds__(256, 2) void out_gemm_kernel(
    const u16* __restrict__ O1, const u16* __restrict__ O2,
    const float* __restrict__ l1, const float* __restrict__ l2,
    const u16* __restrict__ WpT, const float* __restrict__ bp,
    float* __restrict__ out) {
    __shared__ __align__(16) u16 As[2][128 * 64];
    __shared__ __align__(16) u16 Bs[2][128 * 64];

    const int tid = threadIdx.x;
    const int lane = tid & 63;
    const int wv = tid >> 6;
    const int wm = wv >> 1, wn = wv & 1;
    const int qd = lane >> 4, lr = lane & 15;
    const int m0 = blockIdx.y * 128, n0 = blockIdx.x * 128;
    const int lrow = lane >> 3;
    const int gu = (lane & 7) ^ lrow;

    floatx4 acc[4][4];
#pragma unroll
    for (int i = 0; i < 4; ++i)
#pragma unroll
        for (int j = 0; j < 4; ++j) {
            floatx4 zz = {0.f, 0.f, 0.f, 0.f};
            acc[i][j] = zz;
        }

    uint4 p1[4], p2[4];
    float la_[4], lb_[4];

#define LOAD_AO(tt)                                                                \
    {                                                                              \
        _Pragma("unroll") for (int j = 0; j < 4; ++j) {                            \
            int c = wv * 4 + j;                                                    \
            int row = m0 + c * 8 + lrow;                                           \
            int col = (tt)*64 + gu * 8;                                            \
            p1[j] = *(const uint4*)(O1 + (size_t)row * E_ + col);                  \
            p2[j] = *(const uint4*)(O2 + (size_t)row * E_ + col);                  \
            int li = (row >> 11) * (H_ * L_) + (tt)*L_ + (row & (L_ - 1));         \
            la_[j] = l1[li];                                                       \
            lb_[j] = l2[li];                                                       \
        }                                                                          \
    }

#define WRITE_AO(buf)                                                              \
    {                                                                              \
        _Pragma("unroll") for (int j = 0; j < 4; ++j) {                            \
            int c = wv * 4 + j;                                                    \
            float s = 1.0f / (la_[j] + lb_[j]);                                    \
            float w1 = la_[j] * s, w2 = lb_[j] * s;                                \
            const u32* pa = (const u32*)&p1[j];                                    \
            const u32* pb = (const u32*)&p2[j];                                    \
            uint4 o;                                                               \
            u32* po = (u32*)&o;                                                    \
            _Pragma("unroll") for (int d = 0; d < 4; ++d) {                        \
                union { u32 u; float f; } x0, x1, y0, y1;                          \
                x0.u = pa[d] << 16; x1.u = pa[d] & 0xFFFF0000u;                    \
                y0.u = pb[d] << 16; y1.u = pb[d] & 0xFFFF0000u;                    \
                po[d] = cvt_pk_bf16(x0.f * w1 + y0.f * w2, x1.f * w1 + y1.f * w2); \
            }                                                                      \
            *(uint4*)(&As[buf][c * 512 + lane * 8]) = o;                           \
        }                                                                          \
    }

#define STAGE_BO(buf, kb)                                                          \
    {                                                                              \
        _Pragma("unroll") for (int j = 0; j < 4; ++j) {                            \
            int c = wv * 4 + j;                                                    \
            glds16(WpT + (size_t)(n0 + c * 8 + lrow) * E_ + (kb) + gu * 8,         \
                   &Bs[buf][c * 512]);                                             \
        }                                                                          \
    }

    LOAD_AO(0)
    STAGE_BO(0, 0)
    WRITE_AO(0)
    __syncthreads();

    for (int t = 0; t < 16; ++t) {
        const int cur = t & 1;
        if (t + 1 < 16) {
            STAGE_BO(cur ^ 1, (t + 1) * 64)
            LOAD_AO(t + 1)
        }

        short8 af[4][2], bf[4][2];
#pragma unroll
        for (int mi = 0; mi < 4; ++mi)
#pragma unroll
            for (int kk = 0; kk < 2; ++kk) {
                int row = wm * 64 + mi * 16 + lr;
                int u = (kk * 4 + qd) ^ (lr & 7);
                af[mi][kk] = *(const short8*)(&As[cur][row * 64 + u * 8]);
            }
#pragma unroll
        for (int ni = 0; ni < 4; ++ni)
#pragma unroll
            for (int kk = 0; kk < 2; ++kk) {
                int row = wn * 64 + ni * 16 + lr;
                int u = (kk * 4 + qd) ^ (lr & 7);
                bf[ni][kk] = *(const short8*)(&Bs[cur][row * 64 + u * 8]);
            }
#pragma unroll
        for (int kk = 0; kk < 2; ++kk)
#pragma unroll
            for (int mi = 0; mi < 4; ++mi)
#pragma unroll
                for (int ni = 0; ni < 4; ++ni)
                    acc[mi][ni] = __builtin_amdgcn_mfma_f32_16x16x32_bf16(
                        af[mi][kk], bf[ni][kk], acc[mi][ni], 0, 0, 0);

        if (t + 1 < 16) WRITE_AO(cur ^ 1)
        __syncthreads();
    }

#pragma unroll
    for (int mi = 0; mi < 4; ++mi)
#pragma unroll
        for (int ni = 0; ni < 4; ++ni) {
            int col = n0 + wn * 64 + ni * 16 + lr;
            float bv_ = bp[col];
#pragma unroll
            for (int r = 0; r < 4; ++r) {
                int row = m0 + wm * 64 + mi * 16 + qd * 4 + r;
                out[(size_t)row * E_ + col] = acc[mi][ni][r] + bv_;
            }
        }
#undef LOAD_AO
#undef WRITE_AO
#undef STAGE_BO
}

// ---------------------------------------------------------------------------
extern "C" void kernel_launch(void* const* d_in, const int* in_sizes, int n_in,
                              void* d_out, int out_size, void* d_ws, size_t ws_size,
                              hipStream_t stream) {
    const float* x   = (const float*)d_in[0];
    const float* ctx = (const float*)d_in[1];
    const float* Wq  = (const float*)d_in[2];
    const float* bq  = (const float*)d_in[3];
    const float* Wk  = (const float*)d_in[4];
    const float* bk  = (const float*)d_in[5];
    const float* Wv  = (const float*)d_in[6];
    const float* bv  = (const float*)d_in[7];
    const float* Wp  = (const float*)d_in[8];
    const float* bp  = (const float*)d_in[9];
    float* out = (float*)d_out;

    // workspace (u16 elems): WqT..WpT 4x1M | Qb 4M | Kb 4M | Vtb 4M |
    // Opart 2x4M | lpart 2x64K f32   (~48.5 MB total)
    u16* WqT = (u16*)d_ws;
    u16* WkT = WqT + 1048576;
    u16* WvT = WkT + 1048576;
    u16* WpT = WvT + 1048576;
    u16* Qb  = WpT + 1048576;
    u16* Kb  = Qb + 4194304;
    u16* Vtb = Kb + 4194304;
    u16* Opart = Vtb + 4194304;
    float* lpart = (float*)(Opart + 2 * 4194304);
    (void)ws_size; (void)in_sizes; (void)n_in; (void)out_size;

    transpose_cast_kernel<<<dim3(32, 32, 4), dim3(32, 8), 0, stream>>>(
        Wq, Wk, Wv, Wp, WqT, WkT, WvT, WpT);

    qkv_gemm_kernel<<<dim3(8, 32, 3), 256, 0, stream>>>(
        x, ctx, WqT, WkT, WvT, bq, bk, bv, Qb, Kb, Vtb);

    flash_attn_kernel<<<dim3(L_ / 128, B_ * H_, 2), 256, 0, stream>>>(
        Qb, Kb, Vtb, Opart, lpart);

    out_gemm_kernel<<<dim3(8, 32), 256, 0, stream>>>(
        Opart, Opart + 4194304, lpart, lpart + B_ * H_ * L_, WpT, bp, out);
}

// Round 7
// 238.746 us; speedup vs baseline: 1.1739x; 1.1739x over previous
//
#include <hip/hip_runtime.h>
#include <math.h>

// Problem constants
#define B_ 2
#define L_ 2048
#define S_ 2048
#define E_ 1024
#define H_ 16
#define D_ 64
#define SC_ 0.180336880111120f  // (1/sqrt(64)) * log2(e), folded into Q projection

typedef unsigned short u16;
typedef unsigned int u32;
typedef __attribute__((ext_vector_type(8))) short short8;    // 8 bf16 (4 VGPRs)
typedef __attribute__((ext_vector_type(4))) float floatx4;   // 16x16 accum

__device__ __forceinline__ u16 f2bf(float f) {
    union { float f; unsigned u; } a; a.f = f;
    unsigned r = a.u + 0x7FFFu + ((a.u >> 16) & 1u);  // RNE
    return (u16)(r >> 16);
}

// pack two f32 -> bf16x2 (RNE), single instruction
__device__ __forceinline__ u32 cvt_pk_bf16(float lo, float hi) {
    u32 d;
    asm("v_cvt_pk_bf16_f32 %0, %1, %2" : "=v"(d) : "v"(lo), "v"(hi));
    return d;
}

// async global->LDS, 16B per lane; LDS dest = wave-uniform base + lane*16
__device__ __forceinline__ void glds16(const u16* g, u16* l) {
    __builtin_amdgcn_global_load_lds(
        (const __attribute__((address_space(1))) void*)g,
        (__attribute__((address_space(3))) void*)l, 16, 0, 0);
}

// ---------------------------------------------------------------------------
// f32 -> bf16 cast; grid.y selects (x->Xb, ctx->Cb)
// ---------------------------------------------------------------------------
__global__ void cast_bf16_kernel(const float* __restrict__ x, const float* __restrict__ ctx,
                                 u16* __restrict__ Xb, u16* __restrict__ Cb) {
    const float* src = blockIdx.y ? ctx : x;
    u16* dst = blockIdx.y ? Cb : Xb;
    int i = blockIdx.x * 256 + threadIdx.x;
    float4 u0 = ((const float4*)src)[2 * i];
    float4 u1 = ((const float4*)src)[2 * i + 1];
    uint4 o;
    o.x = cvt_pk_bf16(u0.x, u0.y);
    o.y = cvt_pk_bf16(u0.z, u0.w);
    o.z = cvt_pk_bf16(u1.x, u1.y);
    o.w = cvt_pk_bf16(u1.z, u1.w);
    ((uint4*)dst)[i] = o;
}

// ---------------------------------------------------------------------------
// Weight transpose+cast: Wt[n][k] = bf16(W[k][n]); grid.z selects weight
// ---------------------------------------------------------------------------
__global__ void transpose_cast_kernel(const float* __restrict__ Wq, const float* __restrict__ Wk,
                                      const float* __restrict__ Wv, const float* __restrict__ Wp,
                                      u16* __restrict__ WqT, u16* __restrict__ WkT,
                                      u16* __restrict__ WvT, u16* __restrict__ WpT) {
    const int z = blockIdx.z;
    const float* W = z == 0 ? Wq : (z == 1 ? Wk : (z == 2 ? Wv : Wp));
    u16* Wt = z == 0 ? WqT : (z == 1 ? WkT : (z == 2 ? WvT : WpT));
    __shared__ float tile[32][33];
    const int bx = blockIdx.x * 32, by = blockIdx.y * 32;
    const int tx = threadIdx.x, ty = threadIdx.y;  // block (32, 8)
#pragma unroll
    for (int j = 0; j < 4; ++j)
        tile[ty + j * 8][tx] = W[(size_t)(by + ty + j * 8) * E_ + bx + tx];
    __syncthreads();
#pragma unroll
    for (int j = 0; j < 4; ++j)
        Wt[(size_t)(bx + ty + j * 8) * E_ + by + tx] = f2bf(tile[tx][ty + j * 8]);
}

// ---------------------------------------------------------------------------
// XCD-aware block remap for (8 n-tiles) x (32 m-tiles) grids.
// lin%8 ~ XCD id; all 8 n-blocks of one m-strip share lin%8 (same XCD L2),
// so each A-strip is fetched from HBM once per chip, not 8x.
// ---------------------------------------------------------------------------
__device__ __forceinline__ void xcd_remap(int bx, int by, int& m_idx, int& n_idx) {
    int lin = bx + 8 * by;       // 0..255
    int c8 = lin & 7;            // ~XCD
    int g = lin >> 3;            // 0..31
    m_idx = c8 + 8 * (g & 3);    // 0..31 ; m_idx % 8 == c8
    n_idx = g >> 2;              // 0..7
}

// ---------------------------------------------------------------------------
// Fused QKV projection GEMM: BM=128 BN=128 BK=64, 256 threads, wave-tile
// 64x64 (4x4 16x16x32 accum), DOUBLE-buffered LDS via glds16 for A and B,
// 1 barrier/iter, XOR-swizzled LDS (unit' = unit ^ (row&7)), XCD remap.
// grid (8, 32, 3): z=0: Q=(x Wq+bq)*SC -> Qb ; z=1: K -> Kb ; z=2: V -> Vtb
// (V transposed: Vt[b][col][s]). A inputs are pre-cast bf16 (Xb/Cb).
// ---------------------------------------------------------------------------
__global__ __launch_bounds__(256, 2) void qkv_gemm_kernel(
    const u16* __restrict__ Xb, const u16* __restrict__ Cb,
    const u16* __restrict__ WqT, const u16* __restrict__ WkT, const u16* __restrict__ WvT,
    const float* __restrict__ bq, const float* __restrict__ bk, const float* __restrict__ bv,
    u16* __restrict__ Qb, u16* __restrict__ Kb, u16* __restrict__ Vtb) {
    __shared__ __align__(16) u16 As[2][128 * 64];  // 2 x 16 KB
    __shared__ __align__(16) u16 Bs[2][128 * 64];  // 2 x 16 KB

    const int z = blockIdx.z;
    const u16* A  = z == 0 ? Xb : Cb;
    const u16* Bt = z == 0 ? WqT : (z == 1 ? WkT : WvT);
    const float* bias = z == 0 ? bq : (z == 1 ? bk : bv);
    const float scale = z == 0 ? SC_ : 1.0f;

    const int tid = threadIdx.x;
    const int lane = tid & 63;
    const int wv = tid >> 6;
    const int wm = wv >> 1, wn = wv & 1;
    const int qd = lane >> 4, lr = lane & 15;
    int m_idx, n_idx;
    xcd_remap(blockIdx.x, blockIdx.y, m_idx, n_idx);
    const int m0 = m_idx * 128, n0 = n_idx * 128;
    const int lrow = lane >> 3;        // 0..7
    const int gu = (lane & 7) ^ lrow;  // swizzled global 16B-unit

    floatx4 acc[4][4];
#pragma unroll
    for (int i = 0; i < 4; ++i)
#pragma unroll
        for (int j = 0; j < 4; ++j) {
            floatx4 zz = {0.f, 0.f, 0.f, 0.f};
            acc[i][j] = zz;
        }

#define STAGE_AB(buf, kb)                                                          \
    {                                                                              \
        _Pragma("unroll") for (int j = 0; j < 4; ++j) {                            \
            int c = wv * 4 + j;                                                    \
            glds16(A + (size_t)(m0 + c * 8 + lrow) * E_ + (kb) + gu * 8,           \
                   &As[buf][c * 512]);                                             \
            glds16(Bt + (size_t)(n0 + c * 8 + lrow) * E_ + (kb) + gu * 8,          \
                   &Bs[buf][c * 512]);                                             \
        }                                                                          \
    }

    STAGE_AB(0, 0)
    __syncthreads();  // tile 0 landed (vmcnt drained at barrier)

    for (int t = 0; t < 16; ++t) {
        const int cur = t & 1;
        if (t + 1 < 16) STAGE_AB(cur ^ 1, (t + 1) * 64)

        short8 af[4][2], bf[4][2];
#pragma unroll
        for (int mi = 0; mi < 4; ++mi)
#pragma unroll
            for (int kk = 0; kk < 2; ++kk) {
                int row = wm * 64 + mi * 16 + lr;
                int u = (kk * 4 + qd) ^ (lr & 7);
                af[mi][kk] = *(const short8*)(&As[cur][row * 64 + u * 8]);
            }
#pragma unroll
        for (int ni = 0; ni < 4; ++ni)
#pragma unroll
            for (int kk = 0; kk < 2; ++kk) {
                int row = wn * 64 + ni * 16 + lr;
                int u = (kk * 4 + qd) ^ (lr & 7);
                bf[ni][kk] = *(const short8*)(&Bs[cur][row * 64 + u * 8]);
            }
#pragma unroll
        for (int kk = 0; kk < 2; ++kk)
#pragma unroll
            for (int mi = 0; mi < 4; ++mi)
#pragma unroll
                for (int ni = 0; ni < 4; ++ni)
                    acc[mi][ni] = __builtin_amdgcn_mfma_f32_16x16x32_bf16(
                        af[mi][kk], bf[ni][kk], acc[mi][ni], 0, 0, 0);

        __syncthreads();  // readers done with cur; prefetch into cur^1 drained
    }

    // epilogue: C/D row = qd*4+r, col = lane&15
    u16* Cq = z == 0 ? Qb : Kb;
#pragma unroll
    for (int mi = 0; mi < 4; ++mi) {
#pragma unroll
        for (int ni = 0; ni < 4; ++ni) {
            int col = n0 + wn * 64 + ni * 16 + lr;
            float bv_ = bias[col];
            if (z == 2) {
                int row0 = m0 + wm * 64 + mi * 16 + qd * 4;
                int bidx = row0 >> 11;
                int sloc = row0 & (S_ - 1);
                u16 h0 = f2bf(acc[mi][ni][0] + bv_);
                u16 h1 = f2bf(acc[mi][ni][1] + bv_);
                u16 h2 = f2bf(acc[mi][ni][2] + bv_);
                u16 h3 = f2bf(acc[mi][ni][3] + bv_);
                uint2 pk;
                pk.x = h0 | ((unsigned)h1 << 16);
                pk.y = h2 | ((unsigned)h3 << 16);
                *(uint2*)&Vtb[((size_t)(bidx * E_ + col)) * S_ + sloc] = pk;
            } else {
#pragma unroll
                for (int r = 0; r < 4; ++r) {
                    int row = m0 + wm * 64 + mi * 16 + qd * 4 + r;
                    Cq[(size_t)row * E_ + col] = f2bf((acc[mi][ni][r] + bv_) * scale);
                }
            }
        }
    }
#undef STAGE_AB
}

// ---------------------------------------------------------------------------
// Flash attention (r5-verified math + double-buffered K/V, 1 barrier/iter):
// grid (L/128, B*H, 2), 256 threads (4 waves). Wave w owns Q rows
// [w*32, w*32+32). Fixed-reference softmax (M=0; scale folded into Q):
// p = exp2(qk'). P round-trips through wave-private LDS rows (PSTR=68).
// K row-major and V^T staged via XOR-swizzled glds (conflict-free b128).
// Outputs: NORMALIZED O-partial (bf16) + l-partial (f32).
// ---------------------------------------------------------------------------
#define PSTR 68  // P/Q LDS row stride in halfwords

__global__ __launch_bounds__(256, 3) void flash_attn_kernel(
    const u16* __restrict__ Q, const u16* __restrict__ Kg,
    const u16* __restrict__ Vtg, u16* __restrict__ Opart, float* __restrict__ lpart) {
    __shared__ __align__(16) u16 Ps[128 * PSTR];  // Q tile then P (17408 B)
    __shared__ __align__(16) u16 Ks[2][64 * 64];  // 2 x 8 KB (swizzled)
    __shared__ __align__(16) u16 Vs[2][64 * 64];  // 2 x 8 KB, V^T layout [d][s]

    const int tid = threadIdx.x;
    const int lane = tid & 63;
    const int wv = tid >> 6;
    const int qd = lane >> 4, lr = lane & 15;
    const int b = blockIdx.y >> 4, h = blockIdx.y & 15;
    const int q0 = blockIdx.x * 128;
    const int z = blockIdx.z;
    const int sbeg = z * (S_ / 2);

    u16* Op = Opart + (size_t)z * (B_ * L_ * E_);
    float* lp = lpart + (size_t)z * (B_ * H_ * L_);

    const u16* Qbase = Q + (size_t)(b * L_ + q0) * E_ + h * D_;
    const u16* Kbase = Kg + (size_t)(b * S_) * E_ + h * D_;
    const u16* Vbase = Vtg + (size_t)(b * E_ + h * D_) * S_;  // rows=d, cols=s

    const int srow = tid >> 3;        // 0..31
    const int scol = (tid & 7) * 8;   // 0..56
    const int lrow = lane >> 3;       // 0..7
    const int gu = (lane & 7) ^ lrow; // swizzled global 16B-unit

    // issue K/V tile 0 loads first (in flight during Q staging)
#pragma unroll
    for (int j = 0; j < 2; ++j) {
        int c = wv * 2 + j;
        glds16(Kbase + (size_t)(sbeg + c * 8 + lrow) * E_ + gu * 8, &Ks[0][c * 512]);
        glds16(Vbase + (size_t)(c * 8 + lrow) * S_ + sbeg + gu * 8, &Vs[0][c * 512]);
    }

    // stage Q tile (128 x 64) at stride PSTR
#pragma unroll
    for (int c = 0; c < 4; ++c) {
        int row = srow + c * 32;
        *(uint4*)(&Ps[row * PSTR + scol]) = *(const uint4*)(Qbase + (size_t)row * E_ + scol);
    }
    __syncthreads();  // Q staged; K/V tile 0 landed

    short8 qf[2][2];
#pragma unroll
    for (int mi = 0; mi < 2; ++mi)
#pragma unroll
        for (int kk = 0; kk < 2; ++kk)
            qf[mi][kk] = *(const short8*)(&Ps[(wv * 32 + mi * 16 + lr) * PSTR + kk * 32 + qd * 8]);

    floatx4 o_acc[2][4];
    float l_acc[2][4];
#pragma unroll
    for (int mi = 0; mi < 2; ++mi)
#pragma unroll
        for (int nt = 0; nt < 4; ++nt) {
            floatx4 z4 = {0.f, 0.f, 0.f, 0.f};
            o_acc[mi][nt] = z4;
        }
#pragma unroll
    for (int mi = 0; mi < 2; ++mi)
#pragma unroll
        for (int r = 0; r < 4; ++r) l_acc[mi][r] = 0.f;

    const int NIT = (S_ / 2) / 64;  // 16

    for (int it = 0; it < NIT; ++it) {
        const int cur = it & 1;
        // prefetch next K/V tile into the other buffer (in flight during compute)
        if (it + 1 < NIT) {
            int s1 = sbeg + (it + 1) * 64;
#pragma unroll
            for (int j = 0; j < 2; ++j) {
                int c = wv * 2 + j;
                glds16(Kbase + (size_t)(s1 + c * 8 + lrow) * E_ + gu * 8, &Ks[cur ^ 1][c * 512]);
                glds16(Vbase + (size_t)(c * 8 + lrow) * S_ + s1 + gu * 8, &Vs[cur ^ 1][c * 512]);
            }
        }

        // ---- S' = Q K^T (scale already folded into Q) ----
        floatx4 s_[2][4];
#pragma unroll
        for (int nt = 0; nt < 4; ++nt) {
            int krow = nt * 16 + lr;
            short8 kb0 = *(const short8*)(&Ks[cur][krow * 64 + ((qd) ^ (lr & 7)) * 8]);
            short8 kb1 = *(const short8*)(&Ks[cur][krow * 64 + ((4 + qd) ^ (lr & 7)) * 8]);
#pragma unroll
            for (int mi = 0; mi < 2; ++mi) {
                floatx4 zz = {0.f, 0.f, 0.f, 0.f};
                zz = __builtin_amdgcn_mfma_f32_16x16x32_bf16(qf[mi][0], kb0, zz, 0, 0, 0);
                zz = __builtin_amdgcn_mfma_f32_16x16x32_bf16(qf[mi][1], kb1, zz, 0, 0, 0);
                s_[mi][nt] = zz;
            }
        }

        // ---- p = exp2(s'); accumulate l; write P (wave-private rows) ----
#pragma unroll
        for (int mi = 0; mi < 2; ++mi)
#pragma unroll
            for (int nt = 0; nt < 4; ++nt)
#pragma unroll
                for (int r = 0; r < 4; ++r) {
                    float p = __builtin_amdgcn_exp2f(s_[mi][nt][r]);
                    l_acc[mi][r] += p;
                    Ps[(wv * 32 + mi * 16 + qd * 4 + r) * PSTR + nt * 16 + lr] = f2bf(p);
                }
        asm volatile("s_waitcnt lgkmcnt(0)" ::: "memory");  // order P write->read (wave-local)

        // ---- O += P V ----
        short8 pf[2][2];
#pragma unroll
        for (int mi = 0; mi < 2; ++mi)
#pragma unroll
            for (int kk = 0; kk < 2; ++kk)
                pf[mi][kk] = *(const short8*)(&Ps[(wv * 32 + mi * 16 + lr) * PSTR + kk * 32 + qd * 8]);
#pragma unroll
        for (int nt = 0; nt < 4; ++nt) {
            int vrow = nt * 16 + lr;
            short8 vb0 = *(const short8*)(&Vs[cur][vrow * 64 + ((qd) ^ (lr & 7)) * 8]);
            short8 vb1 = *(const short8*)(&Vs[cur][vrow * 64 + ((4 + qd) ^ (lr & 7)) * 8]);
#pragma unroll
            for (int mi = 0; mi < 2; ++mi) {
                o_acc[mi][nt] = __builtin_amdgcn_mfma_f32_16x16x32_bf16(pf[mi][0], vb0, o_acc[mi][nt], 0, 0, 0);
                o_acc[mi][nt] = __builtin_amdgcn_mfma_f32_16x16x32_bf16(pf[mi][1], vb1, o_acc[mi][nt], 0, 0, 0);
            }
        }

        __syncthreads();  // readers done with cur; prefetch into cur^1 drained
    }

    // ---- epilogue: l reduction; write l and NORMALIZED O partial ----
    float linv[2][4];
#pragma unroll
    for (int mi = 0; mi < 2; ++mi)
#pragma unroll
        for (int r = 0; r < 4; ++r) {
            float l = l_acc[mi][r];
#pragma unroll
            for (int st = 1; st < 16; st <<= 1) l += __shfl_xor(l, st);
            if (lr == 0)
                lp[(size_t)(b * H_ + h) * L_ + q0 + wv * 32 + mi * 16 + qd * 4 + r] = l;
            linv[mi][r] = 1.0f / l;
        }

#pragma unroll
    for (int mi = 0; mi < 2; ++mi)
#pragma unroll
        for (int nt = 0; nt < 4; ++nt)
#pragma unroll
            for (int r = 0; r < 4; ++r) {
                int row = q0 + wv * 32 + mi * 16 + qd * 4 + r;
                int col = h * D_ + nt * 16 + lr;
                Op[(size_t)(b * L_ + row) * E_ + col] = f2bf(o_acc[mi][nt][r] * linv[mi][r]);
            }
}

// ---------------------------------------------------------------------------
// Output GEMM with fused split-S combine: A = w1*O1~ + w2*O2~ (normalized
// partials, wi = li/(l1+l2), per (row, head=k-iter)). C = A*WpT^T + bp, f32.
// BM=128 BN=128 BK=64, DOUBLE-buffered LDS, 1 barrier/iter, XCD remap.
// A combine VGPR-prefetched at iter top, applied post-MFMA; B swizzled glds.
// ---------------------------------------------------------------------------
__global__ __launch_bounds__(256, 2) void out_gemm_kernel(
    const u16* __restrict__ O1, const u16* __restrict__ O2,
    const float* __restrict__ l1, const float* __restrict__ l2,
    const u16* __restrict__ WpT, const float* __restrict__ bp,
    float* __restrict__ out) {
    __shared__ __align__(16) u16 As[2][128 * 64];
    __shared__ __align__(16) u16 Bs[2][128 * 64];

    const int tid = threadIdx.x;
    const int lane = tid & 63;
    const int wv = tid >> 6;
    const int wm = wv >> 1, wn = wv & 1;
    const int qd = lane >> 4, lr = lane & 15;
    int m_idx, n_idx;
    xcd_remap(blockIdx.x, blockIdx.y, m_idx, n_idx);
    const int m0 = m_idx * 128, n0 = n_idx * 128;
    const int lrow = lane >> 3;
    const int gu = (lane & 7) ^ lrow;

    floatx4 acc[4][4];
#pragma unroll
    for (int i = 0; i < 4; ++i)
#pragma unroll
        for (int j = 0; j < 4; ++j) {
            floatx4 zz = {0.f, 0.f, 0.f, 0.f};
            acc[i][j] = zz;
        }

    uint4 p1[4], p2[4];
    float la_[4], lb_[4];

#define LOAD_AO(tt)                                                                \
    {                                                                              \
        _Pragma("unroll") for (int j = 0; j < 4; ++j) {                            \
            int c = wv * 4 + j;                                                    \
            int row = m0 + c * 8 + lrow;                                           \
            int col = (tt)*64 + gu * 8;                                            \
            p1[j] = *(const uint4*)(O1 + (size_t)row * E_ + col);                  \
            p2[j] = *(const uint4*)(O2 + (size_t)row * E_ + col);                  \
            int li = (row >> 11) * (H_ * L_) + (tt)*L_ + (row & (L_ - 1));         \
            la_[j] = l1[li];                                                       \
            lb_[j] = l2[li];                                                       \
        }                                                                          \
    }

#define WRITE_AO(buf)                                                              \
    {                                                                              \
        _Pragma("unroll") for (int j = 0; j < 4; ++j) {                            \
            int c = wv * 4 + j;                                                    \
            float s = 1.0f / (la_[j] + lb_[j]);                                    \
            float w1 = la_[j] * s, w2 = lb_[j] * s;                                \
            const u32* pa = (const u32*)&p1[j];                                    \
            const u32* pb = (const u32*)&p2[j];                                    \
            uint4 o;                                                               \
            u32* po = (u32*)&o;                                                    \
            _Pragma("unroll") for (int d = 0; d < 4; ++d) {                        \
                union { u32 u; float f; } x0, x1, y0, y1;                          \
                x0.u = pa[d] << 16; x1.u = pa[d] & 0xFFFF0000u;                    \
                y0.u = pb[d] << 16; y1.u = pb[d] & 0xFFFF0000u;                    \
                po[d] = cvt_pk_bf16(x0.f * w1 + y0.f * w2, x1.f * w1 + y1.f * w2); \
            }                                                                      \
            *(uint4*)(&As[buf][c * 512 + lane * 8]) = o;                           \
        }                                                                          \
    }

#define STAGE_BO(buf, kb)                                                          \
    {                                                                              \
        _Pragma("unroll") for (int j = 0; j < 4; ++j) {                            \
            int c = wv * 4 + j;                                                    \
            glds16(WpT + (size_t)(n0 + c * 8 + lrow) * E_ + (kb) + gu * 8,         \
                   &Bs[buf][c * 512]);                                             \
        }                                                                          \
    }

    LOAD_AO(0)
    STAGE_BO(0, 0)
    WRITE_AO(0)
    __syncthreads();

    for (int t = 0; t < 16; ++t) {
        const int cur = t & 1;
        if (t + 1 < 16) {
            STAGE_BO(cur ^ 1, (t + 1) * 64)
            LOAD_AO(t + 1)
        }

        short8 af[4][2], bf[4][2];
#pragma unroll
        for (int mi = 0; mi < 4; ++mi)
#pragma unroll
            for (int kk = 0; kk < 2; ++kk) {
                int row = wm * 64 + mi * 16 + lr;
                int u = (kk * 4 + qd) ^ (lr & 7);
                af[mi][kk] = *(const short8*)(&As[cur][row * 64 + u * 8]);
            }
#pragma unroll
        for (int ni = 0; ni < 4; ++ni)
#pragma unroll
            for (int kk = 0; kk < 2; ++kk) {
                int row = wn * 64 + ni * 16 + lr;
                int u = (kk * 4 + qd) ^ (lr & 7);
                bf[ni][kk] = *(const short8*)(&Bs[cur][row * 64 + u * 8]);
            }
#pragma unroll
        for (int kk = 0; kk < 2; ++kk)
#pragma unroll
            for (int mi = 0; mi < 4; ++mi)
#pragma unroll
                for (int ni = 0; ni < 4; ++ni)
                    acc[mi][ni] = __builtin_amdgcn_mfma_f32_16x16x32_bf16(
                        af[mi][kk], bf[ni][kk], acc[mi][ni], 0, 0, 0);

        if (t + 1 < 16) WRITE_AO(cur ^ 1)
        __syncthreads();
    }

#pragma unroll
    for (int mi = 0; mi < 4; ++mi)
#pragma unroll
        for (int ni = 0; ni < 4; ++ni) {
            int col = n0 + wn * 64 + ni * 16 + lr;
            float bv_ = bp[col];
#pragma unroll
            for (int r = 0; r < 4; ++r) {
                int row = m0 + wm * 64 + mi * 16 + qd * 4 + r;
                out[(size_t)row * E_ + col] = acc[mi][ni][r] + bv_;
            }
        }
#undef LOAD_AO
#undef WRITE_AO
#undef STAGE_BO
}

// ---------------------------------------------------------------------------
extern "C" void kernel_launch(void* const* d_in, const int* in_sizes, int n_in,
                              void* d_out, int out_size, void* d_ws, size_t ws_size,
                              hipStream_t stream) {
    const float* x   = (const float*)d_in[0];
    const float* ctx = (const float*)d_in[1];
    const float* Wq  = (const float*)d_in[2];
    const float* bq  = (const float*)d_in[3];
    const float* Wk  = (const float*)d_in[4];
    const float* bk  = (const float*)d_in[5];
    const float* Wv  = (const float*)d_in[6];
    const float* bv  = (const float*)d_in[7];
    const float* Wp  = (const float*)d_in[8];
    const float* bp  = (const float*)d_in[9];
    float* out = (float*)d_out;

    // workspace (u16 elems): WqT..WpT 4x1M | Qb 4M | Kb 4M | Vtb 4M |
    // Xb 4M | Cb 4M (Xb/Cb reused as Opart[0/1] after projections) | lpart
    u16* WqT = (u16*)d_ws;
    u16* WkT = WqT + 1048576;
    u16* WvT = WkT + 1048576;
    u16* WpT = WvT + 1048576;
    u16* Qb  = WpT + 1048576;
    u16* Kb  = Qb + 4194304;
    u16* Vtb = Kb + 4194304;
    u16* Xb  = Vtb + 4194304;
    u16* Cb  = Xb + 4194304;
    u16* Opart = Xb;  // overlays Xb/Cb (dead after projections)
    float* lpart = (float*)(Cb + 4194304);
    (void)ws_size; (void)in_sizes; (void)n_in; (void)out_size;

    cast_bf16_kernel<<<dim3(2048, 2), 256, 0, stream>>>(x, ctx, Xb, Cb);
    transpose_cast_kernel<<<dim3(32, 32, 4), dim3(32, 8), 0, stream>>>(
        Wq, Wk, Wv, Wp, WqT, WkT, WvT, WpT);

    qkv_gemm_kernel<<<dim3(8, 32, 3), 256, 0, stream>>>(
        Xb, Cb, WqT, WkT, WvT, bq, bk, bv, Qb, Kb, Vtb);

    flash_attn_kernel<<<dim3(L_ / 128, B_ * H_, 2), 256, 0, stream>>>(
        Qb, Kb, Vtb, Opart, lpart);

    out_gemm_kernel<<<dim3(8, 32), 256, 0, stream>>>(
        Opart, Opart + 4194304, lpart, lpart + B_ * H_ * L_, WpT, bp, out);
}